// Round 1
// baseline (157.399 us; speedup 1.0000x reference)
//
#include <hip/hip_runtime.h>

namespace {
constexpr int L = 32, T = 64, D = 8192, H = 16;
constexpr int M = L * T;          // 2048 hutch rows
constexpr int KP = 4;             // k-split in trace kernel (2048 d each)

// workspace layout (floats)
constexpr size_t WS_WCAT = 0;                      // [32][8192] stacked W2^T ; W1
constexpr size_t WS_PRE  = WS_WCAT + 32 * 8192;    // [32][8][16] preact partials
constexpr size_t WS_AC   = WS_PRE + 32 * 8 * 16;   // [KP][2048][32] a/c partials
constexpr size_t WS_BSUM = WS_AC + (size_t)KP * M * 32; // [8]
}

// K0: wcat[c][d] = (c<16) ? W2[d][c] : W1[c-16][d]
__global__ void k_prep_wcat(const float* __restrict__ W1,
                            const float* __restrict__ W2,
                            float* __restrict__ wcat) {
  int b = blockIdx.x, tid = threadIdx.x;
  if (b < 32) {
    int d = b * 256 + tid;
    const float4* src = reinterpret_cast<const float4*>(W2 + (size_t)d * 16);
    float4 q0 = src[0], q1 = src[1], q2 = src[2], q3 = src[3];
    float v[16] = {q0.x, q0.y, q0.z, q0.w, q1.x, q1.y, q1.z, q1.w,
                   q2.x, q2.y, q2.z, q2.w, q3.x, q3.y, q3.z, q3.w};
#pragma unroll
    for (int c = 0; c < 16; ++c) wcat[(size_t)c * D + d] = v[c];
  } else {
    const float4* src = reinterpret_cast<const float4*>(W1);
    float4* dst = reinterpret_cast<float4*>(wcat + (size_t)16 * D);
    int q = (b - 32) * 256 + tid;  // 8192 threads, 32768 float4s
#pragma unroll
    for (int j = 0; j < 4; ++j) dst[q + j * 8192] = src[q + j * 8192];
  }
}

// K1: pre_partial[l][kc][h] = sum over d-chunk of u[l,d]*W1[h,d]
__global__ void k_preact(const float* __restrict__ u,
                         const float* __restrict__ W1,
                         float* __restrict__ pre_partial) {
  int kc = blockIdx.x, l = blockIdx.y, tid = threadIdx.x;
  int d0 = kc * 1024;
  float acc[16];
#pragma unroll
  for (int h = 0; h < 16; ++h) acc[h] = 0.f;
#pragma unroll
  for (int i = 0; i < 4; ++i) {
    int d = d0 + i * 256 + tid;
    float uv = u[(size_t)l * D + d];
#pragma unroll
    for (int h = 0; h < 16; ++h) acc[h] = fmaf(uv, W1[(size_t)h * D + d], acc[h]);
  }
#pragma unroll
  for (int h = 0; h < 16; ++h)
    for (int off = 1; off < 64; off <<= 1) acc[h] += __shfl_xor(acc[h], off);
  __shared__ float red[4][16];
  int lane = tid & 63, wv = tid >> 6;
  if (lane == 0) {
#pragma unroll
    for (int h = 0; h < 16; ++h) red[wv][h] = acc[h];
  }
  __syncthreads();
  if (tid < 16)
    pre_partial[((size_t)l * 8 + kc) * 16 + tid] =
        red[0][tid] + red[1][tid] + red[2][tid] + red[3][tid];
}

// K2: f[l][d] = b2[d] + sum_h tanh(pre[l][h]) * W2[d][h]
__global__ void k_f(const float* __restrict__ pre_partial,
                    const float* __restrict__ b1,
                    const float* __restrict__ W2,
                    const float* __restrict__ b2,
                    float* __restrict__ fout) {
  __shared__ float hl[8][16];
  int tid = threadIdx.x;
  int lg = blockIdx.y;
  if (tid < 128) {
    int ll = tid >> 4, h = tid & 15, l = lg * 8 + ll;
    float p = b1[h];
#pragma unroll
    for (int kc = 0; kc < 8; ++kc) p += pre_partial[((size_t)l * 8 + kc) * 16 + h];
    hl[ll][h] = tanhf(p);
  }
  __syncthreads();
  int d = blockIdx.x * 256 + tid;
  const float4* w2r = reinterpret_cast<const float4*>(W2 + (size_t)d * 16);
  float4 q0 = w2r[0], q1 = w2r[1], q2 = w2r[2], q3 = w2r[3];
  float w2v[16] = {q0.x, q0.y, q0.z, q0.w, q1.x, q1.y, q1.z, q1.w,
                   q2.x, q2.y, q2.z, q2.w, q3.x, q3.y, q3.z, q3.w};
  float bv = b2[d];
#pragma unroll
  for (int ll = 0; ll < 8; ++ll) {
    float fv = bv;
#pragma unroll
    for (int h = 0; h < 16; ++h) fv = fmaf(hl[ll][h], w2v[h], fv);
    fout[(size_t)(lg * 8 + ll) * D + d] = fv;
  }
}

// K3: a/c partial GEMM. Block = (kp, tgroup of 8 rows, l); 4 waves split 32 cols.
__global__ __launch_bounds__(256, 4) void k_trace_ac(
    const float* __restrict__ w, const float* __restrict__ wcat,
    float* __restrict__ ac_partial) {
  int tid = threadIdx.x;
  int kp = blockIdx.x, tg = blockIdx.y, l = blockIdx.z;
  int kt = tid & 63, hg = tid >> 6;
  const float* wb = w + (size_t)(l * 64 + tg * 8) * D + kp * 2048;
  const float* cbase = wcat + (size_t)(hg * 8) * D + kp * 2048;
  float acc[8][8];
#pragma unroll
  for (int g = 0; g < 8; ++g)
#pragma unroll
    for (int c = 0; c < 8; ++c) acc[g][c] = 0.f;

  for (int i = 0; i < 8; ++i) {
    int d = i * 256 + kt * 4;
    float4 wc[8];
#pragma unroll
    for (int c = 0; c < 8; ++c)
      wc[c] = *reinterpret_cast<const float4*>(cbase + (size_t)c * D + d);
#pragma unroll
    for (int g = 0; g < 8; ++g) {
      float4 wv = *reinterpret_cast<const float4*>(wb + (size_t)g * D + d);
#pragma unroll
      for (int c = 0; c < 8; ++c) {
        float t = fmaf(wv.x, wc[c].x, acc[g][c]);
        t = fmaf(wv.y, wc[c].y, t);
        t = fmaf(wv.z, wc[c].z, t);
        acc[g][c] = fmaf(wv.w, wc[c].w, t);
      }
    }
  }
  // butterfly reduce over the 64 lanes of this wave
#pragma unroll
  for (int g = 0; g < 8; ++g)
#pragma unroll
    for (int c = 0; c < 8; ++c)
      for (int off = 1; off < 64; off <<= 1)
        acc[g][c] += __shfl_xor(acc[g][c], off);

  int row0 = l * 64 + tg * 8;
#pragma unroll
  for (int g = 0; g < 8; ++g) {
    if (kt == g) {
      float* dst = ac_partial + ((size_t)kp * M + row0 + g) * 32 + hg * 8;
#pragma unroll
      for (int c = 0; c < 8; ++c) dst[c] = acc[g][c];
    }
  }
}

// K4a: per-row trace = sum_h s[l,h]*a[h]*c[h]; block-reduce
__global__ void k_trace_red(const float* __restrict__ ac_partial,
                            const float* __restrict__ pre_partial,
                            const float* __restrict__ b1,
                            float* __restrict__ bsum) {
  __shared__ float sl[32][16];
  __shared__ float red[4];
  int tid = threadIdx.x;
#pragma unroll
  for (int r = 0; r < 2; ++r) {
    int m = tid * 2 + r;  // 0..511 -> (l,h)
    int l = m >> 4, h = m & 15;
    float p = b1[h];
#pragma unroll
    for (int kc = 0; kc < 8; ++kc) p += pre_partial[((size_t)l * 8 + kc) * 16 + h];
    float t = tanhf(p);
    sl[l][h] = 1.f - t * t;
  }
  __syncthreads();
  int m = blockIdx.x * 256 + tid, l = m >> 6;
  float av[16], cv[16];
#pragma unroll
  for (int h = 0; h < 16; ++h) { av[h] = 0.f; cv[h] = 0.f; }
  for (int p = 0; p < KP; ++p) {
    const float4* src =
        reinterpret_cast<const float4*>(ac_partial + ((size_t)p * M + m) * 32);
#pragma unroll
    for (int j = 0; j < 4; ++j) {
      float4 q = src[j];
      av[j * 4 + 0] += q.x; av[j * 4 + 1] += q.y;
      av[j * 4 + 2] += q.z; av[j * 4 + 3] += q.w;
    }
#pragma unroll
    for (int j = 0; j < 4; ++j) {
      float4 q = src[4 + j];
      cv[j * 4 + 0] += q.x; cv[j * 4 + 1] += q.y;
      cv[j * 4 + 2] += q.z; cv[j * 4 + 3] += q.w;
    }
  }
  float tr = 0.f;
#pragma unroll
  for (int h = 0; h < 16; ++h) tr = fmaf(sl[l][h] * av[h], cv[h], tr);
  for (int off = 1; off < 64; off <<= 1) tr += __shfl_xor(tr, off);
  if ((tid & 63) == 0) red[tid >> 6] = tr;
  __syncthreads();
  if (tid == 0) bsum[blockIdx.x] = red[0] + red[1] + red[2] + red[3];
}

// K4b: final mean
__global__ void k_final(const float* __restrict__ bsum, float* __restrict__ out) {
  int tid = threadIdx.x;  // 64
  float v = (tid < 8) ? bsum[tid] : 0.f;
  for (int off = 1; off < 8; off <<= 1) v += __shfl_xor(v, off);
  if (tid == 0) out[(size_t)L * D] = v * (1.0f / (float)(L * T));
}

extern "C" void kernel_launch(void* const* d_in, const int* in_sizes, int n_in,
                              void* d_out, int out_size, void* d_ws, size_t ws_size,
                              hipStream_t stream) {
  const float* u  = (const float*)d_in[0];
  const float* w  = (const float*)d_in[1];
  const float* W1 = (const float*)d_in[2];
  const float* b1 = (const float*)d_in[3];
  const float* W2 = (const float*)d_in[4];
  const float* b2 = (const float*)d_in[5];
  float* out = (float*)d_out;
  float* ws  = (float*)d_ws;
  float* wcat = ws + WS_WCAT;
  float* pre  = ws + WS_PRE;
  float* ac   = ws + WS_AC;
  float* bsum = ws + WS_BSUM;

  hipLaunchKernelGGL(k_prep_wcat, dim3(64), dim3(256), 0, stream, W1, W2, wcat);
  hipLaunchKernelGGL(k_preact,    dim3(8, 32), dim3(256), 0, stream, u, W1, pre);
  hipLaunchKernelGGL(k_f,         dim3(32, 4), dim3(256), 0, stream, pre, b1, W2, b2, out);
  hipLaunchKernelGGL(k_trace_ac,  dim3(KP, 8, 32), dim3(256), 0, stream, w, wcat, ac);
  hipLaunchKernelGGL(k_trace_red, dim3(8), dim3(256), 0, stream, ac, pre, b1, bsum);
  hipLaunchKernelGGL(k_final,     dim3(1), dim3(64), 0, stream, bsum, out);
}

// Round 4
// 132.364 us; speedup vs baseline: 1.1891x; 1.1891x over previous
//
#include <hip/hip_runtime.h>

typedef __attribute__((ext_vector_type(8))) short bf16x8;
typedef __attribute__((ext_vector_type(4))) float f32x4;

namespace {
constexpr int L = 32, T = 64, D = 8192, H = 16;
constexpr int M = L * T;      // 2048 hutch rows
constexpr int KP = 16;        // k-split in trace kernel
constexpr int CHUNK = D / KP; // 512

// workspace layout (in floats) — keep total small (proven-safe budget ~2 MB)
constexpr size_t WS_WH  = 0;                          // wcat_hi: 32*8192 ushort = 131072 floats
constexpr size_t WS_WL  = WS_WH + 32 * 8192 / 2;      // wcat_lo: 32*8192 ushort
constexpr size_t WS_PRE = WS_WL + 32 * 8192 / 2;      // [32][8][16] preact partials
constexpr size_t WS_AC  = WS_PRE + 32 * 8 * 16;       // [M][32] fp32 accum (atomicAdd)
// total = 131072*2 + 4096 + 65536 floats = 1.33 MB
}

// split f into bf16 hi (truncated) + bf16 lo s.t. hi+lo ~= f to ~2^-16 rel
__device__ inline void split1(float f, short& h, short& l) {
  unsigned b = __float_as_uint(f);
  h = (short)(b >> 16);
  float lf = f - __uint_as_float(b & 0xFFFF0000u);  // exact remainder
  l = (short)(__float_as_uint(lf) >> 16);
}

__device__ inline void split8(float4 a0, float4 a1, bf16x8& h, bf16x8& l) {
  float f[8] = {a0.x, a0.y, a0.z, a0.w, a1.x, a1.y, a1.z, a1.w};
#pragma unroll
  for (int i = 0; i < 8; ++i) {
    short hh, ll;
    split1(f[i], hh, ll);
    h[i] = hh; l[i] = ll;
  }
}

// K0: wcat[c][d] = (c<16) ? W2[d][c] : W1[c-16][d], split to bf16 hi/lo.
// Also zeroes the atomic accumulators (trace scalar slot + ac buffer).
__global__ void k_prep_wcat(const float* __restrict__ W1,
                            const float* __restrict__ W2,
                            ushort* __restrict__ wh, ushort* __restrict__ wl,
                            float* __restrict__ ac, float* __restrict__ out) {
  int b = blockIdx.x, tid = threadIdx.x;
  if (b == 0 && tid == 0) out[(size_t)L * D] = 0.f;
  if (b < 32) {
    int d = b * 256 + tid;
    const float4* src = reinterpret_cast<const float4*>(W2 + (size_t)d * 16);
    float4 q0 = src[0], q1 = src[1], q2 = src[2], q3 = src[3];
    float v[16] = {q0.x, q0.y, q0.z, q0.w, q1.x, q1.y, q1.z, q1.w,
                   q2.x, q2.y, q2.z, q2.w, q3.x, q3.y, q3.z, q3.w};
#pragma unroll
    for (int c = 0; c < 16; ++c) {
      short hh, ll;
      split1(v[c], hh, ll);
      wh[(size_t)c * D + d] = (ushort)hh;
      wl[(size_t)c * D + d] = (ushort)ll;
    }
  } else if (b < 64) {
    // W1: 16*8192 = 131072 floats = 32768 float4s; 32 blocks x 256 thr x 4 each
    int q = (b - 32) * 256 + tid;  // 0..8191
#pragma unroll
    for (int j = 0; j < 4; ++j) {
      int idx = (q + j * 8192) * 4;
      float4 qv = *reinterpret_cast<const float4*>(W1 + idx);
      short h0, l0, h1, l1, h2, l2, h3, l3;
      split1(qv.x, h0, l0); split1(qv.y, h1, l1);
      split1(qv.z, h2, l2); split1(qv.w, h3, l3);
      ushort4 vh = {(ushort)h0, (ushort)h1, (ushort)h2, (ushort)h3};
      ushort4 vl = {(ushort)l0, (ushort)l1, (ushort)l2, (ushort)l3};
      *reinterpret_cast<ushort4*>(wh + (size_t)16 * D + idx) = vh;
      *reinterpret_cast<ushort4*>(wl + (size_t)16 * D + idx) = vl;
    }
  } else {
    // zero ac: M*32 = 65536 floats = 16384 float4; 16 blocks x 256 thr x 4 each
    int t = (b - 64) * 256 + tid;  // 0..4095
    float4 z = {0.f, 0.f, 0.f, 0.f};
    float4* dst = reinterpret_cast<float4*>(ac);
#pragma unroll
    for (int j = 0; j < 4; ++j) dst[t + j * 4096] = z;
  }
}

// K1: pre_partial[l][kc][h] = sum over d-chunk of u[l,d]*W1[h,d] (float4 loads)
__global__ void k_preact(const float* __restrict__ u,
                         const float* __restrict__ W1,
                         float* __restrict__ pre_partial) {
  int kc = blockIdx.x, l = blockIdx.y, tid = threadIdx.x;
  int d = kc * 1024 + tid * 4;
  float4 uv = *reinterpret_cast<const float4*>(u + (size_t)l * D + d);
  float acc[16];
#pragma unroll
  for (int h = 0; h < 16; ++h) {
    float4 wv = *reinterpret_cast<const float4*>(W1 + (size_t)h * D + d);
    float t = fmaf(uv.x, wv.x, 0.f);
    t = fmaf(uv.y, wv.y, t);
    t = fmaf(uv.z, wv.z, t);
    acc[h] = fmaf(uv.w, wv.w, t);
  }
#pragma unroll
  for (int h = 0; h < 16; ++h)
    for (int off = 1; off < 64; off <<= 1) acc[h] += __shfl_xor(acc[h], off);
  __shared__ float red[4][16];
  int lane = tid & 63, wv_ = tid >> 6;
  if (lane == 0) {
#pragma unroll
    for (int h = 0; h < 16; ++h) red[wv_][h] = acc[h];
  }
  __syncthreads();
  if (tid < 16)
    pre_partial[((size_t)l * 8 + kc) * 16 + tid] =
        red[0][tid] + red[1][tid] + red[2][tid] + red[3][tid];
}

// K2: f[l][d] = b2[d] + sum_h tanh(pre[l][h]) * W2[d][h]
__global__ void k_f(const float* __restrict__ pre_partial,
                    const float* __restrict__ b1,
                    const float* __restrict__ W2,
                    const float* __restrict__ b2,
                    float* __restrict__ fout) {
  __shared__ float hl[8][16];
  int tid = threadIdx.x;
  int lg = blockIdx.y;
  if (tid < 128) {
    int ll = tid >> 4, h = tid & 15, l = lg * 8 + ll;
    float p = b1[h];
#pragma unroll
    for (int kc = 0; kc < 8; ++kc) p += pre_partial[((size_t)l * 8 + kc) * 16 + h];
    hl[ll][h] = tanhf(p);
  }
  __syncthreads();
  int d = blockIdx.x * 256 + tid;
  const float4* w2r = reinterpret_cast<const float4*>(W2 + (size_t)d * 16);
  float4 q0 = w2r[0], q1 = w2r[1], q2 = w2r[2], q3 = w2r[3];
  float w2v[16] = {q0.x, q0.y, q0.z, q0.w, q1.x, q1.y, q1.z, q1.w,
                   q2.x, q2.y, q2.z, q2.w, q3.x, q3.y, q3.z, q3.w};
  float bv = b2[d];
#pragma unroll
  for (int ll = 0; ll < 8; ++ll) {
    float fv = bv;
#pragma unroll
    for (int h = 0; h < 16; ++h) fv = fmaf(hl[ll][h], w2v[h], fv);
    fout[(size_t)(lg * 8 + ll) * D + d] = fv;
  }
}

// K3: a/c partial GEMM via split-bf16 MFMA.
// Block = (kp, rowtile-group); 4 waves, each wave owns one 16-row tile.
// Wave computes D[16 rows][32 cols] over its 512-wide k-chunk with
// mfma_f32_16x16x32_bf16: acc += Ah*Bh + Ah*Bl + Al*Bh (lo*lo dropped).
// kp partials are summed via atomicAdd into ac[M][32] (zeroed by K0).
__global__ __launch_bounds__(256) void k_trace_ac(
    const float* __restrict__ w,
    const ushort* __restrict__ wh, const ushort* __restrict__ wl,
    float* __restrict__ ac) {
  int tid = threadIdx.x;
  int wave = tid >> 6, lane = tid & 63;
  int lrow = lane & 15, kg = lane >> 4;
  int kp = blockIdx.x;
  int rt = blockIdx.y * 4 + wave;   // rowtile 0..127
  int m0 = rt * 16;
  int k0 = kp * CHUNK;

  const float*  wrow = w  + (size_t)(m0 + lrow) * D + k0 + kg * 8;
  const ushort* bh0  = wh + (size_t)lrow * D + k0 + kg * 8;
  const ushort* bl0  = wl + (size_t)lrow * D + k0 + kg * 8;
  const ushort* bh1  = bh0 + (size_t)16 * D;
  const ushort* bl1  = bl0 + (size_t)16 * D;

  f32x4 acc0 = {0.f, 0.f, 0.f, 0.f};
  f32x4 acc1 = {0.f, 0.f, 0.f, 0.f};

  for (int kk = 0; kk < CHUNK / 32; ++kk) {
    int off = kk * 32;
    float4 a0 = *reinterpret_cast<const float4*>(wrow + off);
    float4 a1 = *reinterpret_cast<const float4*>(wrow + off + 4);
    bf16x8 ah, al;
    split8(a0, a1, ah, al);
    bf16x8 vbh0 = *reinterpret_cast<const bf16x8*>(bh0 + off);
    bf16x8 vbl0 = *reinterpret_cast<const bf16x8*>(bl0 + off);
    bf16x8 vbh1 = *reinterpret_cast<const bf16x8*>(bh1 + off);
    bf16x8 vbl1 = *reinterpret_cast<const bf16x8*>(bl1 + off);
    acc0 = __builtin_amdgcn_mfma_f32_16x16x32_bf16(ah, vbh0, acc0, 0, 0, 0);
    acc0 = __builtin_amdgcn_mfma_f32_16x16x32_bf16(ah, vbl0, acc0, 0, 0, 0);
    acc0 = __builtin_amdgcn_mfma_f32_16x16x32_bf16(al, vbh0, acc0, 0, 0, 0);
    acc1 = __builtin_amdgcn_mfma_f32_16x16x32_bf16(ah, vbh1, acc1, 0, 0, 0);
    acc1 = __builtin_amdgcn_mfma_f32_16x16x32_bf16(ah, vbl1, acc1, 0, 0, 0);
    acc1 = __builtin_amdgcn_mfma_f32_16x16x32_bf16(al, vbh1, acc1, 0, 0, 0);
  }

  // C/D layout: col = lane&15, row = (lane>>4)*4 + reg  [measured m89]
  float* dst = ac + (size_t)(m0 + kg * 4) * 32;
#pragma unroll
  for (int j = 0; j < 4; ++j) {
    atomicAdd(dst + (size_t)j * 32 + lrow,      acc0[j]);
    atomicAdd(dst + (size_t)j * 32 + 16 + lrow, acc1[j]);
  }
}

// K4: per-row trace = sum_h s[l,h]*a[h]*c[h]; wave-reduce; atomicAdd mean.
// One block per l (64 rows = 64 threads).
__global__ void k_trace_red(const float* __restrict__ ac,
                            const float* __restrict__ pre_partial,
                            const float* __restrict__ b1,
                            float* __restrict__ out) {
  __shared__ float s[16];
  int tid = threadIdx.x;          // 64
  int l = blockIdx.x;             // 32 blocks
  int m = l * 64 + tid;
  if (tid < 16) {
    float p = b1[tid];
#pragma unroll
    for (int kc = 0; kc < 8; ++kc) p += pre_partial[((size_t)l * 8 + kc) * 16 + tid];
    float t = tanhf(p);
    s[tid] = 1.f - t * t;
  }
  __syncthreads();
  const float4* src = reinterpret_cast<const float4*>(ac + (size_t)m * 32);
  float av[16], cv[16];
#pragma unroll
  for (int j = 0; j < 4; ++j) {
    float4 q = src[j];
    av[j * 4 + 0] = q.x; av[j * 4 + 1] = q.y;
    av[j * 4 + 2] = q.z; av[j * 4 + 3] = q.w;
  }
#pragma unroll
  for (int j = 0; j < 4; ++j) {
    float4 q = src[4 + j];
    cv[j * 4 + 0] = q.x; cv[j * 4 + 1] = q.y;
    cv[j * 4 + 2] = q.z; cv[j * 4 + 3] = q.w;
  }
  float tr = 0.f;
#pragma unroll
  for (int h = 0; h < 16; ++h) tr = fmaf(s[h] * av[h], cv[h], tr);
  for (int off = 1; off < 64; off <<= 1) tr += __shfl_xor(tr, off);
  if (tid == 0) atomicAdd(out + (size_t)L * D, tr * (1.0f / (float)(L * T)));
}

extern "C" void kernel_launch(void* const* d_in, const int* in_sizes, int n_in,
                              void* d_out, int out_size, void* d_ws, size_t ws_size,
                              hipStream_t stream) {
  const float* u  = (const float*)d_in[0];
  const float* w  = (const float*)d_in[1];
  const float* W1 = (const float*)d_in[2];
  const float* b1 = (const float*)d_in[3];
  const float* W2 = (const float*)d_in[4];
  const float* b2 = (const float*)d_in[5];
  float* out = (float*)d_out;
  float* ws  = (float*)d_ws;
  ushort* wcat_h = (ushort*)(ws + WS_WH);
  ushort* wcat_l = (ushort*)(ws + WS_WL);
  float* pre = ws + WS_PRE;
  float* acb = ws + WS_AC;

  hipLaunchKernelGGL(k_prep_wcat, dim3(80), dim3(256), 0, stream, W1, W2, wcat_h, wcat_l, acb, out);
  hipLaunchKernelGGL(k_preact,    dim3(8, 32), dim3(256), 0, stream, u, W1, pre);
  hipLaunchKernelGGL(k_f,         dim3(32, 4), dim3(256), 0, stream, pre, b1, W2, b2, out);
  hipLaunchKernelGGL(k_trace_ac,  dim3(KP, 32), dim3(256), 0, stream, w, wcat_h, wcat_l, acb);
  hipLaunchKernelGGL(k_trace_red, dim3(32), dim3(64), 0, stream, acb, pre, b1, out);
}

// Round 5
// 123.484 us; speedup vs baseline: 1.2746x; 1.0719x over previous
//
#include <hip/hip_runtime.h>

typedef __attribute__((ext_vector_type(8))) short bf16x8;
typedef __attribute__((ext_vector_type(4))) float f32x4;

namespace {
constexpr int L = 32, T = 64, D = 8192, H = 16;
constexpr int M = L * T;      // 2048 hutch rows
constexpr int KP = 32;        // k-split in trace kernel (4 blocks/CU)
constexpr int CHUNK = D / KP; // 256

// workspace layout (in floats); ws_size is ~268 MB, we use ~1.3 MB
constexpr size_t WS_WH  = 0;                          // wcat_hi: 32*8192 ushort
constexpr size_t WS_WL  = WS_WH + 32 * 8192 / 2;      // wcat_lo: 32*8192 ushort
constexpr size_t WS_PRE = WS_WL + 32 * 8192 / 2;      // [32][8][16] preact partials
constexpr size_t WS_AC  = WS_PRE + 32 * 8 * 16;       // [M][32] fp32 accum (atomicAdd)
}

// split f into bf16 hi (truncated) + bf16 lo s.t. hi+lo ~= f to ~2^-16 rel
__device__ inline void split1(float f, short& h, short& l) {
  unsigned b = __float_as_uint(f);
  h = (short)(b >> 16);
  float lf = f - __uint_as_float(b & 0xFFFF0000u);  // exact remainder
  l = (short)(__float_as_uint(lf) >> 16);
}

__device__ inline void split8(float4 a0, float4 a1, bf16x8& h, bf16x8& l) {
  float f[8] = {a0.x, a0.y, a0.z, a0.w, a1.x, a1.y, a1.z, a1.w};
#pragma unroll
  for (int i = 0; i < 8; ++i) {
    short hh, ll;
    split1(f[i], hh, ll);
    h[i] = hh; l[i] = ll;
  }
}

// K1 (fused setup, role-split by blockIdx.x):
//   b in [0,32):   W2 transpose + split -> wcat cols 0..15
//   b in [32,64):  W1 split -> wcat cols 16..31
//   b in [64,80):  zero ac accumulator
//   b in [80,336): preact partials pre[l][kc][h] (kc=(b-80)&7, l=(b-80)>>3)
__global__ __launch_bounds__(256) void k_setup(
    const float* __restrict__ u, const float* __restrict__ W1,
    const float* __restrict__ W2,
    ushort* __restrict__ wh, ushort* __restrict__ wl,
    float* __restrict__ pre, float* __restrict__ ac,
    float* __restrict__ out) {
  int b = blockIdx.x, tid = threadIdx.x;
  if (b == 0 && tid == 0) out[(size_t)L * D] = 0.f;
  if (b < 32) {
    int d = b * 256 + tid;
    const float4* src = reinterpret_cast<const float4*>(W2 + (size_t)d * 16);
    float4 q0 = src[0], q1 = src[1], q2 = src[2], q3 = src[3];
    float v[16] = {q0.x, q0.y, q0.z, q0.w, q1.x, q1.y, q1.z, q1.w,
                   q2.x, q2.y, q2.z, q2.w, q3.x, q3.y, q3.z, q3.w};
#pragma unroll
    for (int c = 0; c < 16; ++c) {
      short hh, ll;
      split1(v[c], hh, ll);
      wh[(size_t)c * D + d] = (ushort)hh;
      wl[(size_t)c * D + d] = (ushort)ll;
    }
  } else if (b < 64) {
    // W1: 131072 floats = 32768 float4s; 32 blocks x 256 thr x 4 float4
    int q = (b - 32) * 256 + tid;  // 0..8191
#pragma unroll
    for (int j = 0; j < 4; ++j) {
      int idx = (q + j * 8192) * 4;
      float4 qv = *reinterpret_cast<const float4*>(W1 + idx);
      short h0, l0, h1, l1, h2, l2, h3, l3;
      split1(qv.x, h0, l0); split1(qv.y, h1, l1);
      split1(qv.z, h2, l2); split1(qv.w, h3, l3);
      ushort4 vh = {(ushort)h0, (ushort)h1, (ushort)h2, (ushort)h3};
      ushort4 vl = {(ushort)l0, (ushort)l1, (ushort)l2, (ushort)l3};
      *reinterpret_cast<ushort4*>(wh + (size_t)16 * D + idx) = vh;
      *reinterpret_cast<ushort4*>(wl + (size_t)16 * D + idx) = vl;
    }
  } else if (b < 80) {
    // zero ac: 65536 floats = 16384 float4; 16 blocks x 256 thr x 4
    int t = (b - 64) * 256 + tid;
    float4 z = {0.f, 0.f, 0.f, 0.f};
    float4* dst = reinterpret_cast<float4*>(ac);
#pragma unroll
    for (int j = 0; j < 4; ++j) dst[t + j * 4096] = z;
  } else {
    int bb = b - 80;
    int kc = bb & 7, l = bb >> 3;
    int d = kc * 1024 + tid * 4;
    float4 uv = *reinterpret_cast<const float4*>(u + (size_t)l * D + d);
    float acc[16];
#pragma unroll
    for (int h = 0; h < 16; ++h) {
      float4 wv = *reinterpret_cast<const float4*>(W1 + (size_t)h * D + d);
      float t = fmaf(uv.x, wv.x, 0.f);
      t = fmaf(uv.y, wv.y, t);
      t = fmaf(uv.z, wv.z, t);
      acc[h] = fmaf(uv.w, wv.w, t);
    }
#pragma unroll
    for (int h = 0; h < 16; ++h)
      for (int off = 1; off < 64; off <<= 1) acc[h] += __shfl_xor(acc[h], off);
    __shared__ float red[4][16];
    int lane = tid & 63, wv_ = tid >> 6;
    if (lane == 0) {
#pragma unroll
      for (int h = 0; h < 16; ++h) red[wv_][h] = acc[h];
    }
    __syncthreads();
    if (tid < 16)
      pre[((size_t)l * 8 + kc) * 16 + tid] =
          red[0][tid] + red[1][tid] + red[2][tid] + red[3][tid];
  }
}

// K2: a/c GEMM via split-bf16 MFMA, atomicAdd kp-partials into ac[M][32].
// Grid (KP=32, 32 rowgroups) = 1024 blocks, 4 waves each (16-row tile/wave).
__global__ __launch_bounds__(256) void k_trace_ac(
    const float* __restrict__ w,
    const ushort* __restrict__ wh, const ushort* __restrict__ wl,
    float* __restrict__ ac) {
  int tid = threadIdx.x;
  int wave = tid >> 6, lane = tid & 63;
  int lrow = lane & 15, kg = lane >> 4;
  int kp = blockIdx.x;
  int rt = blockIdx.y * 4 + wave;   // rowtile 0..127
  int m0 = rt * 16;
  int k0 = kp * CHUNK;

  const float*  wrow = w  + (size_t)(m0 + lrow) * D + k0 + kg * 8;
  const ushort* bh0  = wh + (size_t)lrow * D + k0 + kg * 8;
  const ushort* bl0  = wl + (size_t)lrow * D + k0 + kg * 8;
  const ushort* bh1  = bh0 + (size_t)16 * D;
  const ushort* bl1  = bl0 + (size_t)16 * D;

  f32x4 acc0 = {0.f, 0.f, 0.f, 0.f};
  f32x4 acc1 = {0.f, 0.f, 0.f, 0.f};

#pragma unroll
  for (int kk = 0; kk < CHUNK / 32; ++kk) {
    int off = kk * 32;
    float4 a0 = *reinterpret_cast<const float4*>(wrow + off);
    float4 a1 = *reinterpret_cast<const float4*>(wrow + off + 4);
    bf16x8 ah, al;
    split8(a0, a1, ah, al);
    bf16x8 vbh0 = *reinterpret_cast<const bf16x8*>(bh0 + off);
    bf16x8 vbl0 = *reinterpret_cast<const bf16x8*>(bl0 + off);
    bf16x8 vbh1 = *reinterpret_cast<const bf16x8*>(bh1 + off);
    bf16x8 vbl1 = *reinterpret_cast<const bf16x8*>(bl1 + off);
    acc0 = __builtin_amdgcn_mfma_f32_16x16x32_bf16(ah, vbh0, acc0, 0, 0, 0);
    acc0 = __builtin_amdgcn_mfma_f32_16x16x32_bf16(ah, vbl0, acc0, 0, 0, 0);
    acc0 = __builtin_amdgcn_mfma_f32_16x16x32_bf16(al, vbh0, acc0, 0, 0, 0);
    acc1 = __builtin_amdgcn_mfma_f32_16x16x32_bf16(ah, vbh1, acc1, 0, 0, 0);
    acc1 = __builtin_amdgcn_mfma_f32_16x16x32_bf16(ah, vbl1, acc1, 0, 0, 0);
    acc1 = __builtin_amdgcn_mfma_f32_16x16x32_bf16(al, vbh1, acc1, 0, 0, 0);
  }

  // C/D layout: col = lane&15, row = (lane>>4)*4 + reg  [measured m89]
  float* dst = ac + (size_t)(m0 + kg * 4) * 32;
#pragma unroll
  for (int j = 0; j < 4; ++j) {
    atomicAdd(dst + (size_t)j * 32 + lrow,      acc0[j]);
    atomicAdd(dst + (size_t)j * 32 + 16 + lrow, acc1[j]);
  }
}

// K3 (fused tail, role-split by blockIdx.x):
//   b in [0,128):   f[l][d] = b2[d] + sum_h tanh(pre_l_h) * W2[d][h]
//   b in [128,160): per-row trace + wave reduce + atomicAdd scalar mean
__global__ __launch_bounds__(256) void k_tail(
    const float* __restrict__ pre, const float* __restrict__ b1,
    const float* __restrict__ W2, const float* __restrict__ b2,
    const float* __restrict__ ac, float* __restrict__ out) {
  int b = blockIdx.x, tid = threadIdx.x;
  if (b >= 128) {
    // trace reduction for l = b-128
    __shared__ float s[16];
    int l = b - 128;
    if (tid < 16) {
      float p = b1[tid];
#pragma unroll
      for (int kc = 0; kc < 8; ++kc) p += pre[((size_t)l * 8 + kc) * 16 + tid];
      float t = tanhf(p);
      s[tid] = 1.f - t * t;
    }
    __syncthreads();
    if (tid < 64) {
      int m = l * 64 + tid;
      const float4* src = reinterpret_cast<const float4*>(ac + (size_t)m * 32);
      float av[16], cv[16];
#pragma unroll
      for (int j = 0; j < 4; ++j) {
        float4 q = src[j];
        av[j * 4 + 0] = q.x; av[j * 4 + 1] = q.y;
        av[j * 4 + 2] = q.z; av[j * 4 + 3] = q.w;
      }
#pragma unroll
      for (int j = 0; j < 4; ++j) {
        float4 q = src[4 + j];
        cv[j * 4 + 0] = q.x; cv[j * 4 + 1] = q.y;
        cv[j * 4 + 2] = q.z; cv[j * 4 + 3] = q.w;
      }
      float tr = 0.f;
#pragma unroll
      for (int h = 0; h < 16; ++h) tr = fmaf(s[h] * av[h], cv[h], tr);
      for (int off = 1; off < 64; off <<= 1) tr += __shfl_xor(tr, off);
      if (tid == 0) atomicAdd(out + (size_t)L * D, tr * (1.0f / (float)(L * T)));
    }
    return;
  }
  // f path
  __shared__ float hl[8][16];
  int lg = b >> 5;
  if (tid < 128) {
    int ll = tid >> 4, h = tid & 15, l = lg * 8 + ll;
    float p = b1[h];
#pragma unroll
    for (int kc = 0; kc < 8; ++kc) p += pre[((size_t)l * 8 + kc) * 16 + h];
    hl[ll][h] = tanhf(p);
  }
  __syncthreads();
  int d = (b & 31) * 256 + tid;
  const float4* w2r = reinterpret_cast<const float4*>(W2 + (size_t)d * 16);
  float4 q0 = w2r[0], q1 = w2r[1], q2 = w2r[2], q3 = w2r[3];
  float w2v[16] = {q0.x, q0.y, q0.z, q0.w, q1.x, q1.y, q1.z, q1.w,
                   q2.x, q2.y, q2.z, q2.w, q3.x, q3.y, q3.z, q3.w};
  float bv = b2[d];
#pragma unroll
  for (int ll = 0; ll < 8; ++ll) {
    float fv = bv;
#pragma unroll
    for (int h = 0; h < 16; ++h) fv = fmaf(hl[ll][h], w2v[h], fv);
    out[(size_t)(lg * 8 + ll) * D + d] = fv;
  }
}

extern "C" void kernel_launch(void* const* d_in, const int* in_sizes, int n_in,
                              void* d_out, int out_size, void* d_ws, size_t ws_size,
                              hipStream_t stream) {
  const float* u  = (const float*)d_in[0];
  const float* w  = (const float*)d_in[1];
  const float* W1 = (const float*)d_in[2];
  const float* b1 = (const float*)d_in[3];
  const float* W2 = (const float*)d_in[4];
  const float* b2 = (const float*)d_in[5];
  float* out = (float*)d_out;
  float* ws  = (float*)d_ws;
  ushort* wcat_h = (ushort*)(ws + WS_WH);
  ushort* wcat_l = (ushort*)(ws + WS_WL);
  float* pre = ws + WS_PRE;
  float* acb = ws + WS_AC;

  hipLaunchKernelGGL(k_setup,    dim3(336), dim3(256), 0, stream,
                     u, W1, W2, wcat_h, wcat_l, pre, acb, out);
  hipLaunchKernelGGL(k_trace_ac, dim3(KP, 32), dim3(256), 0, stream,
                     w, wcat_h, wcat_l, acb);
  hipLaunchKernelGGL(k_tail,     dim3(160), dim3(256), 0, stream,
                     pre, b1, W2, b2, acb, out);
}